// Round 13
// baseline (536.159 us; speedup 1.0000x reference)
//
#include <hip/hip_runtime.h>
#include <hip/hip_cooperative_groups.h>

namespace cg = cooperative_groups;

// GAT forward: bf16-MFMA projections fused with edge-count, then ONE
// cooperative kernel for {blocksum, scan, scatter, aggregate}.
// N=50000, E=800000, IN_DIM=128, H=8, D=16.

#define NEG_SLOPE 0.2f
#define CB 1024   // count-role blocks fused into proj kernel
#define GB 1024   // cooperative grid blocks (4 blocks/CU guaranteed)

typedef __attribute__((ext_vector_type(8))) short short8;   // 8 bf16
typedef __attribute__((ext_vector_type(4))) float f32x4;    // MFMA C/D frag

__device__ __forceinline__ unsigned short f2bf(float f) {
    unsigned int u = __builtin_bit_cast(unsigned int, f);
    u = (u + 0x7fffu + ((u >> 16) & 1u)) >> 16;   // RNE
    return (unsigned short)u;
}
__device__ __forceinline__ float bf2f(unsigned short s) {
    unsigned int u = (unsigned int)s << 16;
    return __builtin_bit_cast(float, u);
}

// ---------------------------------------------------------------------------
// Kernel 1: zero cnt + csr pad + pack weights to MFMA-fragment-linear bf16.
// ---------------------------------------------------------------------------
__global__ __launch_bounds__(256) void zero_wconv_kernel(
    const float* __restrict__ Wq, const float* __restrict__ Wk,
    const float* __restrict__ Wv, const float* __restrict__ Wres,
    unsigned short* __restrict__ wpk, int* __restrict__ cnt,
    int* __restrict__ csr_pad, int n4)
{
    int t = blockIdx.x * 256 + threadIdx.x;
    if (t < 8192) {
        int l = t & 63;
        int v = t >> 6;
        int kk = v & 3;
        int wct = v >> 2;
        int ct = wct & 7;
        int w = wct >> 3;
        const float* W = (w == 0) ? Wq : (w == 1) ? Wk : (w == 2) ? Wv : Wres;
        const float* srcp = W + (size_t)(ct * 16 + (l & 15)) * 128 + kk * 32 + (l >> 4) * 8;
        float4 lo = *reinterpret_cast<const float4*>(srcp);
        float4 hi = *reinterpret_cast<const float4*>(srcp + 4);
        short8 o;
        o[0] = (short)f2bf(lo.x); o[1] = (short)f2bf(lo.y);
        o[2] = (short)f2bf(lo.z); o[3] = (short)f2bf(lo.w);
        o[4] = (short)f2bf(hi.x); o[5] = (short)f2bf(hi.y);
        o[6] = (short)f2bf(hi.z); o[7] = (short)f2bf(hi.w);
        *reinterpret_cast<short8*>(wpk + (size_t)t * 8) = o;
        if (t < 64) csr_pad[t] = 0;   // zero the prefetch pad past csr_src[E]
    } else {
        int u = t - 8192;
        if (u < n4) reinterpret_cast<int4*>(cnt)[u] = make_int4(0, 0, 0, 0);
    }
}

// ---------------------------------------------------------------------------
// Kernel 2: MFMA projections + fused edge-count.
// q,k,res -> bf16; v -> int8 with per-row scale (vscl[n] = rowmax/127).
// ---------------------------------------------------------------------------
__global__ __launch_bounds__(256) void proj_count_kernel(
    const float* __restrict__ h,
    const unsigned short* __restrict__ wpk,
    unsigned short* __restrict__ qb, unsigned short* __restrict__ kb,
    signed char* __restrict__ vi8, float* __restrict__ vscl,
    unsigned short* __restrict__ resb,
    const int* __restrict__ dst, int* __restrict__ cnt,
    int N, int E, int PB)
{
    if (blockIdx.x >= PB) {
        int start = (blockIdx.x - PB) * 256 + threadIdx.x;
        for (int e = start; e < E; e += CB * 256)
            atomicAdd(&cnt[dst[e]], 1);
        return;
    }

    const int wid = threadIdx.x >> 6;
    const int lane = threadIdx.x & 63;
    const int row0 = blockIdx.x * 128 + wid * 32;
    const int r = lane & 15, g = lane >> 4;

    short8 afrag[2][4];
    #pragma unroll
    for (int grp = 0; grp < 2; ++grp) {
        int arow = row0 + grp * 16 + r;
        if (arow >= N) arow = N - 1;
        const float* hrow = h + (size_t)arow * 128 + g * 8;
        #pragma unroll
        for (int kk = 0; kk < 4; ++kk) {
            float4 lo = *reinterpret_cast<const float4*>(hrow + kk * 32);
            float4 hi = *reinterpret_cast<const float4*>(hrow + kk * 32 + 4);
            short8 a;
            a[0] = (short)f2bf(lo.x); a[1] = (short)f2bf(lo.y);
            a[2] = (short)f2bf(lo.z); a[3] = (short)f2bf(lo.w);
            a[4] = (short)f2bf(hi.x); a[5] = (short)f2bf(hi.y);
            a[6] = (short)f2bf(hi.z); a[7] = (short)f2bf(hi.w);
            afrag[grp][kk] = a;
        }
    }

    // ---- q (w=0), k (w=1), res (w=3): per-ct accumulators, bf16 stores ----
    #pragma unroll
    for (int sec = 0; sec < 3; ++sec) {
        const int w = (sec == 0) ? 0 : (sec == 1) ? 1 : 3;
        unsigned short* O = (sec == 0) ? qb : (sec == 1) ? kb : resb;
        #pragma unroll
        for (int ct = 0; ct < 8; ++ct) {
            const unsigned short* bp =
                wpk + ((size_t)((w * 8 + ct) * 4) * 64 + lane) * 8;
            f32x4 acc[2];
            acc[0] = (f32x4)(0.f); acc[1] = (f32x4)(0.f);
            #pragma unroll
            for (int kk = 0; kk < 4; ++kk) {
                short8 bfrag = *reinterpret_cast<const short8*>(bp + (size_t)kk * 512);
                acc[0] = __builtin_amdgcn_mfma_f32_16x16x32_bf16(
                    afrag[0][kk], bfrag, acc[0], 0, 0, 0);
                acc[1] = __builtin_amdgcn_mfma_f32_16x16x32_bf16(
                    afrag[1][kk], bfrag, acc[1], 0, 0, 0);
            }
            #pragma unroll
            for (int grp = 0; grp < 2; ++grp)
                #pragma unroll
                for (int j = 0; j < 4; ++j) {
                    int orow = row0 + grp * 16 + g * 4 + j;
                    if (orow < N)
                        O[(size_t)orow * 128 + ct * 16 + r] = f2bf(acc[grp][j]);
                }
        }
    }

    // ---- v (w=2): full-row accumulate, 16-lane row-max, int8 quantize ----
    {
        f32x4 av[2][8];
        #pragma unroll
        for (int grp = 0; grp < 2; ++grp)
            #pragma unroll
            for (int ct = 0; ct < 8; ++ct) av[grp][ct] = (f32x4)(0.f);

        #pragma unroll
        for (int ct = 0; ct < 8; ++ct) {
            const unsigned short* bp =
                wpk + ((size_t)((2 * 8 + ct) * 4) * 64 + lane) * 8;
            #pragma unroll
            for (int kk = 0; kk < 4; ++kk) {
                short8 bfrag = *reinterpret_cast<const short8*>(bp + (size_t)kk * 512);
                av[0][ct] = __builtin_amdgcn_mfma_f32_16x16x32_bf16(
                    afrag[0][kk], bfrag, av[0][ct], 0, 0, 0);
                av[1][ct] = __builtin_amdgcn_mfma_f32_16x16x32_bf16(
                    afrag[1][kk], bfrag, av[1][ct], 0, 0, 0);
            }
        }

        #pragma unroll
        for (int grp = 0; grp < 2; ++grp)
            #pragma unroll
            for (int j = 0; j < 4; ++j) {
                int orow = row0 + grp * 16 + g * 4 + j;
                float m = fabsf(av[grp][0][j]);
                #pragma unroll
                for (int ct = 1; ct < 8; ++ct)
                    m = fmaxf(m, fabsf(av[grp][ct][j]));
                #pragma unroll
                for (int s = 1; s < 16; s <<= 1)
                    m = fmaxf(m, __shfl_xor(m, s, 64));
                float scale = m * (1.f / 127.f);
                float inv = (m > 0.f) ? 127.f / m : 0.f;
                if (orow < N) {
                    #pragma unroll
                    for (int ct = 0; ct < 8; ++ct) {
                        int qv = (int)rintf(av[grp][ct][j] * inv);
                        vi8[(size_t)orow * 128 + ct * 16 + r] = (signed char)qv;
                    }
                    if (r == 0) vscl[orow] = scale;
                }
            }
    }
}

// ---------------------------------------------------------------------------
// Kernel 3 (cooperative): blocksum -> scan -> scatter -> aggregate,
// separated by grid.sync(). 1024 blocks x 256 threads (4 blocks/CU).
// ---------------------------------------------------------------------------
__global__ __launch_bounds__(256, 4) void graph_coop_kernel(
    const unsigned short* __restrict__ qb,
    const unsigned short* __restrict__ kb,
    const unsigned int* __restrict__ vi8_32,
    const float* __restrict__ vscl,
    const unsigned short* __restrict__ resb,
    const int* __restrict__ src, const int* __restrict__ dst,
    int* __restrict__ cnt, int* __restrict__ bsum,
    int* __restrict__ row_start, int* __restrict__ cursor,
    int* __restrict__ csr_src, float* __restrict__ rst,
    int N, int E, int NB)
{
    cg::grid_group grid = cg::this_grid();
    const int tid = threadIdx.x;
    const int lane = tid & 63;

    // ---- Phase A: per-1024-chunk sums of cnt -> bsum ----
    if ((int)blockIdx.x < NB) {
        __shared__ int ws[4];
        int base = blockIdx.x * 1024 + tid * 4;
        int s = 0;
        if (base + 3 < N) {
            int4 v = *reinterpret_cast<const int4*>(cnt + base);
            s = v.x + v.y + v.z + v.w;
        } else {
            for (int i = 0; i < 4; ++i)
                if (base + i < N) s += cnt[base + i];
        }
        #pragma unroll
        for (int m = 32; m >= 1; m >>= 1) s += __shfl_xor(s, m, 64);
        if ((tid & 63) == 0) ws[tid >> 6] = s;
        __syncthreads();
        if (tid == 0) bsum[blockIdx.x] = ws[0] + ws[1] + ws[2] + ws[3];
    }
    grid.sync();

    // ---- Phase B: chunk-local scan + inline bsum prefix -> row_start/cursor ----
    if ((int)blockIdx.x < NB) {
        __shared__ int sboff;
        __shared__ int wsum[4];
        const int w = tid >> 6;

        if (tid < 64) {
            int v = (tid < NB && tid < (int)blockIdx.x) ? bsum[tid] : 0;
            #pragma unroll
            for (int m = 32; m >= 1; m >>= 1) v += __shfl_xor(v, m, 64);
            if (tid == 0) sboff = v;
        }
        __syncthreads();

        int base = blockIdx.x * 1024 + tid * 4;
        int a0 = 0, a1 = 0, a2 = 0, a3 = 0;
        if (base + 3 < N) {
            int4 v = *reinterpret_cast<const int4*>(cnt + base);
            a0 = v.x; a1 = v.y; a2 = v.z; a3 = v.w;
        } else {
            if (base + 0 < N) a0 = cnt[base + 0];
            if (base + 1 < N) a1 = cnt[base + 1];
            if (base + 2 < N) a2 = cnt[base + 2];
            if (base + 3 < N) a3 = cnt[base + 3];
        }
        const int tsum = a0 + a1 + a2 + a3;
        int v = tsum;
        #pragma unroll
        for (int off = 1; off < 64; off <<= 1) {
            int t2 = __shfl_up(v, off, 64);
            if (lane >= off) v += t2;
        }
        if (lane == 63) wsum[w] = v;
        __syncthreads();
        int woff = 0;
        for (int i = 0; i < w; ++i) woff += wsum[i];
        int run = sboff + woff + v - tsum;

        int r0 = run, r1 = run + a0, r2 = r1 + a1, r3 = r2 + a2;
        if (base + 3 < N) {
            int4 o = make_int4(r0, r1, r2, r3);
            *reinterpret_cast<int4*>(row_start + base) = o;
            *reinterpret_cast<int4*>(cursor + base) = o;
        } else {
            int rr[4] = {r0, r1, r2, r3};
            for (int i = 0; i < 4; ++i)
                if (base + i < N) { row_start[base + i] = rr[i]; cursor[base + i] = rr[i]; }
        }
        if (blockIdx.x == 0 && tid == 0) row_start[N] = E;
    }
    grid.sync();

    // ---- Phase C: scatter src into CSR order ----
    for (int e = blockIdx.x * 256 + tid; e < E; e += GB * 256) {
        int d = dst[e];
        int pos = atomicAdd(&cursor[d], 1);
        csr_src[pos] = src[e];
    }
    grid.sync();

    // ---- Phase D: aggregate. One wave per node, grid-strided. ----
    const int j = lane & 31;
    const int half = lane >> 5;
    const int wid = tid >> 6;
    const int nwaves = GB * 4;

    for (int node = blockIdx.x * 4 + wid; node < N; node += nwaves) {
        const int beg = row_start[node];
        const int nE  = row_start[node + 1] - beg;
        const int* cp = csr_src + beg;

        ushort4 qraw = *reinterpret_cast<const ushort4*>(qb + (size_t)node * 128 + 4 * j);
        const float q0 = bf2f(qraw.x), q1 = bf2f(qraw.y),
                    q2 = bf2f(qraw.z), q3 = bf2f(qraw.w);

        float zA = 0.f, zB = 0.f;
        float aA0 = 0.f, aA1 = 0.f, aA2 = 0.f, aA3 = 0.f;
        float aB0 = 0.f, aB1 = 0.f, aB2 = 0.f, aB3 = 0.f;

        if (nE > 0) {
            int sa = cp[half];          // pad past E is zeroed -> safe
            int sb = cp[half + 2];

            for (int i = 0; i < nE; i += 4) {
                const int ii = i + half;
                const float m0 = (ii < nE) ? 1.f : 0.f;
                const float m1 = (ii + 2 < nE) ? 1.f : 0.f;
                const int s0 = sa, s1 = sb;
                sa = cp[ii + 4];
                sb = cp[ii + 6];

                ushort4 k0 = *reinterpret_cast<const ushort4*>(kb + (size_t)s0 * 128 + 4 * j);
                ushort4 k1 = *reinterpret_cast<const ushort4*>(kb + (size_t)s1 * 128 + 4 * j);
                unsigned int w0 = vi8_32[(size_t)s0 * 32 + j];
                unsigned int w1 = vi8_32[(size_t)s1 * 32 + j];
                float sv0 = vscl[s0];
                float sv1 = vscl[s1];

                float p0 = q0 * bf2f(k0.x) + q1 * bf2f(k0.y)
                         + q2 * bf2f(k0.z) + q3 * bf2f(k0.w);
                float p1 = q0 * bf2f(k1.x) + q1 * bf2f(k1.y)
                         + q2 * bf2f(k1.z) + q3 * bf2f(k1.w);
                p0 += __shfl_xor(p0, 1, 64);
                p0 += __shfl_xor(p0, 2, 64);
                p1 += __shfl_xor(p1, 1, 64);
                p1 += __shfl_xor(p1, 2, 64);
                float e0 = (p0 >= 0.f) ? p0 : NEG_SLOPE * p0;
                float e1 = (p1 >= 0.f) ? p1 : NEG_SLOPE * p1;
                e0 = m0 * __expf(e0);
                e1 = m1 * __expf(e1);
                zA += e0;
                zB += e1;
                const float f0 = e0 * sv0;
                const float f1 = e1 * sv1;
                aA0 = fmaf(f0, (float)(signed char)(w0),       aA0);
                aA1 = fmaf(f0, (float)(signed char)(w0 >> 8),  aA1);
                aA2 = fmaf(f0, (float)(signed char)(w0 >> 16), aA2);
                aA3 = fmaf(f0, (float)(signed char)(w0 >> 24), aA3);
                aB0 = fmaf(f1, (float)(signed char)(w1),       aB0);
                aB1 = fmaf(f1, (float)(signed char)(w1 >> 8),  aB1);
                aB2 = fmaf(f1, (float)(signed char)(w1 >> 16), aB2);
                aB3 = fmaf(f1, (float)(signed char)(w1 >> 24), aB3);
            }
        }

        float a0 = aA0 + aB0, a1 = aA1 + aB1, a2 = aA2 + aB2, a3 = aA3 + aB3;
        float z = zA + zB;
        a0 += __shfl_xor(a0, 32, 64);
        a1 += __shfl_xor(a1, 32, 64);
        a2 += __shfl_xor(a2, 32, 64);
        a3 += __shfl_xor(a3, 32, 64);
        z  += __shfl_xor(z, 32, 64);

        if (half == 0) {
            const size_t base = (size_t)node * 128 + 4 * j;
            ushort4 rb = *reinterpret_cast<const ushort4*>(resb + base);
            float inv = (nE > 0) ? 1.f / z : 0.f;
            float4 rv;
            rv.x = fmaf(a0, inv, bf2f(rb.x));
            rv.y = fmaf(a1, inv, bf2f(rb.y));
            rv.z = fmaf(a2, inv, bf2f(rb.z));
            rv.w = fmaf(a3, inv, bf2f(rb.w));
            *reinterpret_cast<float4*>(rst + base) = rv;
        }
    }
}

extern "C" void kernel_launch(void* const* d_in, const int* in_sizes, int n_in,
                              void* d_out, int out_size, void* d_ws, size_t ws_size,
                              hipStream_t stream) {
    const float* h    = (const float*)d_in[0];
    const int*   src  = (const int*)d_in[2];
    const int*   dst  = (const int*)d_in[3];
    const float* Wq   = (const float*)d_in[4];
    const float* Wk   = (const float*)d_in[5];
    const float* Wv   = (const float*)d_in[6];
    const float* Wres = (const float*)d_in[8];
    float* rst = (float*)d_out;

    int N = in_sizes[0] / 128;   // 50000
    int E = in_sizes[2];         // 800000

    unsigned short* qb   = (unsigned short*)d_ws;          // N*128 bf16
    unsigned short* kb   = qb + (size_t)N * 128;           // N*128 bf16
    unsigned short* resb = kb + (size_t)N * 128;           // N*128 bf16
    signed char*    vi8  = (signed char*)(resb + (size_t)N * 128); // N*128 i8
    float*          vscl = (float*)(vi8 + (size_t)N * 128);        // N f32
    unsigned short* wpk  = (unsigned short*)(vscl + N);    // 65536 bf16
    int* cnt       = (int*)(wpk + 4 * 16384);
    int* row_start = cnt + N;          // N+1
    int* cursor    = row_start + (N + 1);
    int* csr_src   = cursor + N;       // E + 64 (padded)
    int* bsum      = csr_src + E + 64;

    const int n4 = N / 4;              // 12500
    int NB = (N + 1023) / 1024;        // 49 <= 64
    const int PB = (N + 127) / 128;    // proj blocks

    zero_wconv_kernel<<<(8192 + n4 + 255) / 256, 256, 0, stream>>>(
        Wq, Wk, Wv, Wres, wpk, cnt, csr_src + E, n4);
    proj_count_kernel<<<PB + CB, 256, 0, stream>>>(
        h, wpk, qb, kb, vi8, vscl, resb, dst, cnt, N, E, PB);

    const unsigned int* vi8_32 = (const unsigned int*)vi8;
    void* args[] = {
        (void*)&qb, (void*)&kb, (void*)&vi8_32, (void*)&vscl, (void*)&resb,
        (void*)&src, (void*)&dst, (void*)&cnt, (void*)&bsum,
        (void*)&row_start, (void*)&cursor, (void*)&csr_src, (void*)&rst,
        (void*)&N, (void*)&E, (void*)&NB
    };
    hipLaunchCooperativeKernel((const void*)graph_coop_kernel,
                               dim3(GB), dim3(256), args, 0, stream);
}

// Round 14
// 158.959 us; speedup vs baseline: 3.3729x; 3.3729x over previous
//
#include <hip/hip_runtime.h>

// GAT forward: bf16-MFMA projections fused with edge-count, CSR scan,
// scatter, fused aggregate with packed int8 k+v single-load gather.
// N=50000, E=800000, IN_DIM=128, H=8, D=16.

#define NEG_SLOPE 0.2f
#define CB 1024   // count-role blocks fused into proj kernel

typedef __attribute__((ext_vector_type(8))) short short8;   // 8 bf16
typedef __attribute__((ext_vector_type(4))) float f32x4;    // MFMA C/D frag

__device__ __forceinline__ unsigned short f2bf(float f) {
    unsigned int u = __builtin_bit_cast(unsigned int, f);
    u = (u + 0x7fffu + ((u >> 16) & 1u)) >> 16;   // RNE
    return (unsigned short)u;
}
__device__ __forceinline__ float bf2f(unsigned short s) {
    unsigned int u = (unsigned int)s << 16;
    return __builtin_bit_cast(float, u);
}

// ---------------------------------------------------------------------------
// Kernel 1: zero cnt + csr pad + pack weights to MFMA-fragment-linear bf16.
// ---------------------------------------------------------------------------
__global__ __launch_bounds__(256) void zero_wconv_kernel(
    const float* __restrict__ Wq, const float* __restrict__ Wk,
    const float* __restrict__ Wv, const float* __restrict__ Wres,
    unsigned short* __restrict__ wpk, int* __restrict__ cnt,
    int* __restrict__ csr_pad, int n4)
{
    int t = blockIdx.x * 256 + threadIdx.x;
    if (t < 8192) {
        int l = t & 63;
        int v = t >> 6;
        int kk = v & 3;
        int wct = v >> 2;
        int ct = wct & 7;
        int w = wct >> 3;
        const float* W = (w == 0) ? Wq : (w == 1) ? Wk : (w == 2) ? Wv : Wres;
        const float* srcp = W + (size_t)(ct * 16 + (l & 15)) * 128 + kk * 32 + (l >> 4) * 8;
        float4 lo = *reinterpret_cast<const float4*>(srcp);
        float4 hi = *reinterpret_cast<const float4*>(srcp + 4);
        short8 o;
        o[0] = (short)f2bf(lo.x); o[1] = (short)f2bf(lo.y);
        o[2] = (short)f2bf(lo.z); o[3] = (short)f2bf(lo.w);
        o[4] = (short)f2bf(hi.x); o[5] = (short)f2bf(hi.y);
        o[6] = (short)f2bf(hi.z); o[7] = (short)f2bf(hi.w);
        *reinterpret_cast<short8*>(wpk + (size_t)t * 8) = o;
        if (t < 64) csr_pad[t] = 0;   // zero the prefetch pad past csr_src[E]
    } else {
        int u = t - 8192;
        if (u < n4) reinterpret_cast<int4*>(cnt)[u] = make_int4(0, 0, 0, 0);
    }
}

// ---------------------------------------------------------------------------
// Kernel 2: MFMA projections + fused edge-count.
// q,res -> bf16.  k,v -> int8 with per-row scales, packed into one 256B row:
//   kvb[n*256 + 8*(c>>2) + (c&3)]     = k_i8[c]
//   kvb[n*256 + 8*(c>>2) + 4 + (c&3)] = v_i8[c]
//   kvscl[2n] = ksc, kvscl[2n+1] = vsc   (value = int8 * scale)
// ---------------------------------------------------------------------------
__global__ __launch_bounds__(256) void proj_count_kernel(
    const float* __restrict__ h,
    const unsigned short* __restrict__ wpk,
    unsigned short* __restrict__ qb, unsigned char* __restrict__ kvb,
    float* __restrict__ kvscl, unsigned short* __restrict__ resb,
    const int* __restrict__ dst, int* __restrict__ cnt,
    int N, int E, int PB)
{
    if (blockIdx.x >= PB) {
        int start = (blockIdx.x - PB) * 256 + threadIdx.x;
        for (int e = start; e < E; e += CB * 256)
            atomicAdd(&cnt[dst[e]], 1);
        return;
    }

    const int wid = threadIdx.x >> 6;
    const int lane = threadIdx.x & 63;
    const int row0 = blockIdx.x * 128 + wid * 32;
    const int r = lane & 15, g = lane >> 4;

    short8 afrag[2][4];
    #pragma unroll
    for (int grp = 0; grp < 2; ++grp) {
        int arow = row0 + grp * 16 + r;
        if (arow >= N) arow = N - 1;
        const float* hrow = h + (size_t)arow * 128 + g * 8;
        #pragma unroll
        for (int kk = 0; kk < 4; ++kk) {
            float4 lo = *reinterpret_cast<const float4*>(hrow + kk * 32);
            float4 hi = *reinterpret_cast<const float4*>(hrow + kk * 32 + 4);
            short8 a;
            a[0] = (short)f2bf(lo.x); a[1] = (short)f2bf(lo.y);
            a[2] = (short)f2bf(lo.z); a[3] = (short)f2bf(lo.w);
            a[4] = (short)f2bf(hi.x); a[5] = (short)f2bf(hi.y);
            a[6] = (short)f2bf(hi.z); a[7] = (short)f2bf(hi.w);
            afrag[grp][kk] = a;
        }
    }

    // ---- q (w=0) and res (w=3): per-ct accumulators, bf16 stores ----
    #pragma unroll
    for (int sec = 0; sec < 2; ++sec) {
        const int w = (sec == 0) ? 0 : 3;
        unsigned short* O = (sec == 0) ? qb : resb;
        #pragma unroll
        for (int ct = 0; ct < 8; ++ct) {
            const unsigned short* bp =
                wpk + ((size_t)((w * 8 + ct) * 4) * 64 + lane) * 8;
            f32x4 acc[2];
            acc[0] = (f32x4)(0.f); acc[1] = (f32x4)(0.f);
            #pragma unroll
            for (int kk = 0; kk < 4; ++kk) {
                short8 bfrag = *reinterpret_cast<const short8*>(bp + (size_t)kk * 512);
                acc[0] = __builtin_amdgcn_mfma_f32_16x16x32_bf16(
                    afrag[0][kk], bfrag, acc[0], 0, 0, 0);
                acc[1] = __builtin_amdgcn_mfma_f32_16x16x32_bf16(
                    afrag[1][kk], bfrag, acc[1], 0, 0, 0);
            }
            #pragma unroll
            for (int grp = 0; grp < 2; ++grp)
                #pragma unroll
                for (int j = 0; j < 4; ++j) {
                    int orow = row0 + grp * 16 + g * 4 + j;
                    if (orow < N)
                        O[(size_t)orow * 128 + ct * 16 + r] = f2bf(acc[grp][j]);
                }
        }
    }

    // ---- k (w=1) then v (w=2): full-row accumulate, row-max, int8 pack ----
    #pragma unroll
    for (int sec = 0; sec < 2; ++sec) {
        const int w = 1 + sec;           // 1 = k, 2 = v
        f32x4 av[2][8];
        #pragma unroll
        for (int grp = 0; grp < 2; ++grp)
            #pragma unroll
            for (int ct = 0; ct < 8; ++ct) av[grp][ct] = (f32x4)(0.f);

        #pragma unroll
        for (int ct = 0; ct < 8; ++ct) {
            const unsigned short* bp =
                wpk + ((size_t)((w * 8 + ct) * 4) * 64 + lane) * 8;
            #pragma unroll
            for (int kk = 0; kk < 4; ++kk) {
                short8 bfrag = *reinterpret_cast<const short8*>(bp + (size_t)kk * 512);
                av[0][ct] = __builtin_amdgcn_mfma_f32_16x16x32_bf16(
                    afrag[0][kk], bfrag, av[0][ct], 0, 0, 0);
                av[1][ct] = __builtin_amdgcn_mfma_f32_16x16x32_bf16(
                    afrag[1][kk], bfrag, av[1][ct], 0, 0, 0);
            }
        }

        #pragma unroll
        for (int grp = 0; grp < 2; ++grp)
            #pragma unroll
            for (int j = 0; j < 4; ++j) {
                int orow = row0 + grp * 16 + g * 4 + j;
                float m = fabsf(av[grp][0][j]);
                #pragma unroll
                for (int ct = 1; ct < 8; ++ct)
                    m = fmaxf(m, fabsf(av[grp][ct][j]));
                #pragma unroll
                for (int s = 1; s < 16; s <<= 1)
                    m = fmaxf(m, __shfl_xor(m, s, 64));
                float scale = m * (1.f / 127.f);
                float inv = (m > 0.f) ? 127.f / m : 0.f;
                if (orow < N) {
                    #pragma unroll
                    for (int ct = 0; ct < 8; ++ct) {
                        int qv = (int)rintf(av[grp][ct][j] * inv);
                        // col c = ct*16+r -> byte 32*ct + 8*(r>>2) + (r&3), +4 for v
                        kvb[(size_t)orow * 256 + 32 * ct + 8 * (r >> 2)
                            + (r & 3) + sec * 4] = (unsigned char)(signed char)qv;
                    }
                    if (r == 0) kvscl[2 * orow + sec] = scale;
                }
            }
    }
}

// ---------------------------------------------------------------------------
// CSR scan: blocksum -> scanfinal (inline 49-element bsum prefix).
// ---------------------------------------------------------------------------
__global__ __launch_bounds__(256) void blocksum_kernel(
    const int* __restrict__ cnt, int* __restrict__ bsum, int N)
{
    __shared__ int ws[4];
    const int tid = threadIdx.x;
    int base = blockIdx.x * 1024 + tid * 4;
    int s = 0;
    if (base + 3 < N) {
        int4 v = *reinterpret_cast<const int4*>(cnt + base);
        s = v.x + v.y + v.z + v.w;
    } else {
        for (int i = 0; i < 4; ++i)
            if (base + i < N) s += cnt[base + i];
    }
    #pragma unroll
    for (int m = 32; m >= 1; m >>= 1) s += __shfl_xor(s, m, 64);
    if ((tid & 63) == 0) ws[tid >> 6] = s;
    __syncthreads();
    if (tid == 0) bsum[blockIdx.x] = ws[0] + ws[1] + ws[2] + ws[3];
}

__global__ __launch_bounds__(256) void scanfinal_kernel(
    const int* __restrict__ cnt, const int* __restrict__ bsum,
    int* __restrict__ row_start, int* __restrict__ cursor,
    int N, int E, int NB)
{
    __shared__ int sboff;
    __shared__ int wsum[4];
    const int tid = threadIdx.x, lane = tid & 63, w = tid >> 6;

    if (tid < 64) {
        int v = (tid < NB && tid < blockIdx.x) ? bsum[tid] : 0;
        #pragma unroll
        for (int m = 32; m >= 1; m >>= 1) v += __shfl_xor(v, m, 64);
        if (tid == 0) sboff = v;
    }
    __syncthreads();

    int base = blockIdx.x * 1024 + tid * 4;
    int a0 = 0, a1 = 0, a2 = 0, a3 = 0;
    if (base + 3 < N) {
        int4 v = *reinterpret_cast<const int4*>(cnt + base);
        a0 = v.x; a1 = v.y; a2 = v.z; a3 = v.w;
    } else {
        if (base + 0 < N) a0 = cnt[base + 0];
        if (base + 1 < N) a1 = cnt[base + 1];
        if (base + 2 < N) a2 = cnt[base + 2];
        if (base + 3 < N) a3 = cnt[base + 3];
    }
    const int tsum = a0 + a1 + a2 + a3;
    int v = tsum;
    #pragma unroll
    for (int off = 1; off < 64; off <<= 1) {
        int t = __shfl_up(v, off, 64);
        if (lane >= off) v += t;
    }
    if (lane == 63) wsum[w] = v;
    __syncthreads();
    int woff = 0;
    for (int i = 0; i < w; ++i) woff += wsum[i];
    int run = sboff + woff + v - tsum;

    int r0 = run, r1 = run + a0, r2 = r1 + a1, r3 = r2 + a2;
    if (base + 3 < N) {
        int4 o = make_int4(r0, r1, r2, r3);
        *reinterpret_cast<int4*>(row_start + base) = o;
        *reinterpret_cast<int4*>(cursor + base) = o;
    } else {
        int rr[4] = {r0, r1, r2, r3};
        for (int i = 0; i < 4; ++i)
            if (base + i < N) { row_start[base + i] = rr[i]; cursor[base + i] = rr[i]; }
    }
    if (blockIdx.x == 0 && tid == 0) row_start[N] = E;
}

__global__ __launch_bounds__(256) void scatter_kernel(
    const int* __restrict__ src, const int* __restrict__ dst,
    int* __restrict__ cursor, int* __restrict__ csr_src, int E)
{
    int e = blockIdx.x * 256 + threadIdx.x;
    if (e < E) {
        int d = dst[e];
        int pos = atomicAdd(&cursor[d], 1);
        csr_src[pos] = src[e];
    }
}

// ---------------------------------------------------------------------------
// Fused score+softmax+aggregate. 32 lanes per edge, 4 edges per wave-iter
// (2 per half). Per lane per edge: ONE uint2 load {4 k-int8, 4 v-int8} +
// one broadcast float2 scale load. k-scale applied once after dot-reduce.
// ---------------------------------------------------------------------------
__global__ __launch_bounds__(256) void fused_agg_kernel(
    const unsigned short* __restrict__ qb,
    const unsigned char* __restrict__ kvb,
    const float2* __restrict__ kvscl,
    const unsigned short* __restrict__ resb,
    const int* __restrict__ row_start, const int* __restrict__ csr_src,
    float* __restrict__ rst, int N)
{
    const int lane = threadIdx.x & 63;
    const int j = lane & 31;
    const int half = lane >> 5;
    const int node = blockIdx.x * 4 + (threadIdx.x >> 6);
    if (node >= N) return;

    const int beg = row_start[node];
    const int nE  = row_start[node + 1] - beg;
    const int* cp = csr_src + beg;

    ushort4 qraw = *reinterpret_cast<const ushort4*>(qb + (size_t)node * 128 + 4 * j);
    const float q0 = bf2f(qraw.x), q1 = bf2f(qraw.y),
                q2 = bf2f(qraw.z), q3 = bf2f(qraw.w);

    float zA = 0.f, zB = 0.f;
    float aA0 = 0.f, aA1 = 0.f, aA2 = 0.f, aA3 = 0.f;
    float aB0 = 0.f, aB1 = 0.f, aB2 = 0.f, aB3 = 0.f;

    if (nE > 0) {
        int sa = cp[half];          // pad past E is zeroed -> safe
        int sb = cp[half + 2];

        for (int i = 0; i < nE; i += 4) {
            const int ii = i + half;
            const float m0 = (ii < nE) ? 1.f : 0.f;
            const float m1 = (ii + 2 < nE) ? 1.f : 0.f;
            const int s0 = sa, s1 = sb;
            sa = cp[ii + 4];
            sb = cp[ii + 6];

            uint2 kv0 = *reinterpret_cast<const uint2*>(kvb + (size_t)s0 * 256 + 8 * j);
            uint2 kv1 = *reinterpret_cast<const uint2*>(kvb + (size_t)s1 * 256 + 8 * j);
            float2 sc0 = kvscl[s0];
            float2 sc1 = kvscl[s1];

            float p0 = q0 * (float)(signed char)(kv0.x)
                     + q1 * (float)(signed char)(kv0.x >> 8)
                     + q2 * (float)(signed char)(kv0.x >> 16)
                     + q3 * (float)(signed char)(kv0.x >> 24);
            float p1 = q0 * (float)(signed char)(kv1.x)
                     + q1 * (float)(signed char)(kv1.x >> 8)
                     + q2 * (float)(signed char)(kv1.x >> 16)
                     + q3 * (float)(signed char)(kv1.x >> 24);
            p0 += __shfl_xor(p0, 1, 64);
            p0 += __shfl_xor(p0, 2, 64);
            p1 += __shfl_xor(p1, 1, 64);
            p1 += __shfl_xor(p1, 2, 64);
            p0 *= sc0.x;
            p1 *= sc1.x;
            float e0 = (p0 >= 0.f) ? p0 : NEG_SLOPE * p0;
            float e1 = (p1 >= 0.f) ? p1 : NEG_SLOPE * p1;
            e0 = m0 * __expf(e0);
            e1 = m1 * __expf(e1);
            zA += e0;
            zB += e1;
            const float f0 = e0 * sc0.y;
            const float f1 = e1 * sc1.y;
            aA0 = fmaf(f0, (float)(signed char)(kv0.y),       aA0);
            aA1 = fmaf(f0, (float)(signed char)(kv0.y >> 8),  aA1);
            aA2 = fmaf(f0, (float)(signed char)(kv0.y >> 16), aA2);
            aA3 = fmaf(f0, (float)(signed char)(kv0.y >> 24), aA3);
            aB0 = fmaf(f1, (float)(signed char)(kv1.y),       aB0);
            aB1 = fmaf(f1, (float)(signed char)(kv1.y >> 8),  aB1);
            aB2 = fmaf(f1, (float)(signed char)(kv1.y >> 16), aB2);
            aB3 = fmaf(f1, (float)(signed char)(kv1.y >> 24), aB3);
        }
    }

    float a0 = aA0 + aB0, a1 = aA1 + aB1, a2 = aA2 + aB2, a3 = aA3 + aB3;
    float z = zA + zB;
    a0 += __shfl_xor(a0, 32, 64);
    a1 += __shfl_xor(a1, 32, 64);
    a2 += __shfl_xor(a2, 32, 64);
    a3 += __shfl_xor(a3, 32, 64);
    z  += __shfl_xor(z, 32, 64);

    if (half == 0) {
        const size_t base = (size_t)node * 128 + 4 * j;
        ushort4 rb = *reinterpret_cast<const ushort4*>(resb + base);
        float inv = (nE > 0) ? 1.f / z : 0.f;
        float4 rv;
        rv.x = fmaf(a0, inv, bf2f(rb.x));
        rv.y = fmaf(a1, inv, bf2f(rb.y));
        rv.z = fmaf(a2, inv, bf2f(rb.z));
        rv.w = fmaf(a3, inv, bf2f(rb.w));
        *reinterpret_cast<float4*>(rst + base) = rv;
    }
}

extern "C" void kernel_launch(void* const* d_in, const int* in_sizes, int n_in,
                              void* d_out, int out_size, void* d_ws, size_t ws_size,
                              hipStream_t stream) {
    const float* h    = (const float*)d_in[0];
    const int*   src  = (const int*)d_in[2];
    const int*   dst  = (const int*)d_in[3];
    const float* Wq   = (const float*)d_in[4];
    const float* Wk   = (const float*)d_in[5];
    const float* Wv   = (const float*)d_in[6];
    const float* Wres = (const float*)d_in[8];
    float* rst = (float*)d_out;

    const int N = in_sizes[0] / 128;   // 50000
    const int E = in_sizes[2];         // 800000

    unsigned short* qb   = (unsigned short*)d_ws;          // N*128 bf16
    unsigned short* resb = qb + (size_t)N * 128;           // N*128 bf16
    unsigned char*  kvb  = (unsigned char*)(resb + (size_t)N * 128); // N*256 u8
    float*          kvscl = (float*)(kvb + (size_t)N * 256);         // 2N f32
    unsigned short* wpk  = (unsigned short*)(kvscl + 2 * N); // 65536 bf16
    int* cnt       = (int*)(wpk + 4 * 16384);
    int* row_start = cnt + N;          // N+1
    int* cursor    = row_start + (N + 1);
    int* csr_src   = cursor + N;       // E + 64 (padded)
    int* bsum      = csr_src + E + 64;

    const int n4 = N / 4;              // 12500
    const int NB = (N + 1023) / 1024;  // 49 <= 64
    const int PB = (N + 127) / 128;    // proj blocks

    zero_wconv_kernel<<<(8192 + n4 + 255) / 256, 256, 0, stream>>>(
        Wq, Wk, Wv, Wres, wpk, cnt, csr_src + E, n4);
    proj_count_kernel<<<PB + CB, 256, 0, stream>>>(
        h, wpk, qb, kvb, kvscl, resb, dst, cnt, N, E, PB);
    blocksum_kernel<<<NB, 256, 0, stream>>>(cnt, bsum, N);
    scanfinal_kernel<<<NB, 256, 0, stream>>>(cnt, bsum, row_start, cursor,
                                             N, E, NB);
    scatter_kernel<<<(E + 255) / 256, 256, 0, stream>>>(src, dst, cursor,
                                                        csr_src, E);
    fused_agg_kernel<<<(N + 3) / 4, 256, 0, stream>>>(
        qb, kvb, (const float2*)kvscl, resb, row_start, csr_src, rst, N);
}